// Round 1
// baseline (504.815 us; speedup 1.0000x reference)
//
#include <hip/hip_runtime.h>

// Zhang-Suen skeletonization: 8 iterations x 2 substeps over (32,512,512,1) fp32.
// Binary state kept as uint8 (0/1). 16 stencil passes, ping-pong buffers.
//
// Neighbor order (reference): P2=N, P3=NE, P4=E, P5=SE, P6=S, P7=SW, P8=W, P9=NW
// delete = on & (2<=bcnt<=6) & (acnt==1) & c1 & c2
//   first=True : c1=!(P2&P4&P6), c2=!(P4&P6&P8)
//   first=False: c1=!(P2&P4&P8), c2=!(P2&P6&P8)

constexpr int W = 512;
constexpr int H = 512;
constexpr int IMG = W * H;          // pixels per image
constexpr int BATCH = 32;
constexpr int TOTAL = BATCH * IMG;  // 8388608

__device__ __forceinline__ int getb(const float* img, int y, int x) {
    if ((unsigned)y >= (unsigned)H || (unsigned)x >= (unsigned)W) return 0;
    return img[y * W + x] >= 0.5f ? 1 : 0;
}
__device__ __forceinline__ int getb(const unsigned char* img, int y, int x) {
    if ((unsigned)y >= (unsigned)H || (unsigned)x >= (unsigned)W) return 0;
    return (int)img[y * W + x];
}

template <bool FIRST, typename InT, typename OutT>
__global__ __launch_bounds__(256) void substep_kernel(const InT* __restrict__ in,
                                                      OutT* __restrict__ out) {
    int idx = blockIdx.x * blockDim.x + threadIdx.x;
    if (idx >= TOTAL) return;
    int x = idx & (W - 1);
    int y = (idx >> 9) & (H - 1);
    const InT* img = in + (idx - (y * W + x));  // image base

    int c = getb(img, y, x);
    int result = 0;
    if (c) {
        int p2 = getb(img, y - 1, x);
        int p3 = getb(img, y - 1, x + 1);
        int p4 = getb(img, y,     x + 1);
        int p5 = getb(img, y + 1, x + 1);
        int p6 = getb(img, y + 1, x);
        int p7 = getb(img, y + 1, x - 1);
        int p8 = getb(img, y,     x - 1);
        int p9 = getb(img, y - 1, x - 1);

        int bcnt = p2 + p3 + p4 + p5 + p6 + p7 + p8 + p9;
        int acnt = ((!p2) & p3) + ((!p3) & p4) + ((!p4) & p5) + ((!p5) & p6) +
                   ((!p6) & p7) + ((!p7) & p8) + ((!p8) & p9) + ((!p9) & p2);

        int c1, c2;
        if (FIRST) {
            c1 = !(p2 & p4 & p6);
            c2 = !(p4 & p6 & p8);
        } else {
            c1 = !(p2 & p4 & p8);
            c2 = !(p2 & p6 & p8);
        }
        int del = (bcnt >= 2) & (bcnt <= 6) & (acnt == 1) & c1 & c2;
        result = c & (del ^ 1);
    }
    out[idx] = (OutT)result;
}

extern "C" void kernel_launch(void* const* d_in, const int* in_sizes, int n_in,
                              void* d_out, int out_size, void* d_ws, size_t ws_size,
                              hipStream_t stream) {
    const float* in0 = (const float*)d_in[0];
    float* out = (float*)d_out;

    unsigned char* A = (unsigned char*)d_ws;
    unsigned char* B;
    if (ws_size >= (size_t)2 * TOTAL) {
        B = A + TOTAL;
    } else {
        // Fall back to using d_out's bytes as scratch. Safe: the final kernel
        // reads only A (in d_ws) and then overwrites all of d_out.
        B = (unsigned char*)d_out;
    }

    const int block = 256;
    const int grid = (TOTAL + block - 1) / block;

    // k1: substep first=True, fp32 input -> u8 A
    substep_kernel<true, float, unsigned char><<<grid, block, 0, stream>>>(in0, A);

    // k2..k15: alternate F,T,F,... on u8 ping-pong
    unsigned char* src = A;
    unsigned char* dst = B;
    bool first = false;
    for (int k = 2; k <= 15; ++k) {
        if (first) {
            substep_kernel<true, unsigned char, unsigned char><<<grid, block, 0, stream>>>(src, dst);
        } else {
            substep_kernel<false, unsigned char, unsigned char><<<grid, block, 0, stream>>>(src, dst);
        }
        unsigned char* t = src; src = dst; dst = t;
        first = !first;
    }

    // k16: substep first=False, u8 (== A after k15) -> fp32 d_out
    substep_kernel<false, unsigned char, float><<<grid, block, 0, stream>>>(src, out);
}

// Round 2
// 150.309 us; speedup vs baseline: 3.3585x; 3.3585x over previous
//
#include <hip/hip_runtime.h>
#include <stdint.h>

// Zhang-Suen skeletonization, bit-packed: 1 bit/pixel, 64 px per u64 word.
// (32, 512, 512) fp32 -> binarize -> 16 bit-parallel substeps -> unpack fp32.
//
// Bit layout: word w covers pixels [w*64, w*64+63] of a row; bit i (LSB=i=0)
// = pixel x = w*64 + i. Row = 512 px = 8 words. Image = 512 rows * 8 words.

constexpr int W = 512;
constexpr int H = 512;
constexpr int BATCH = 32;
constexpr int TOTAL = BATCH * W * H;          // 8388608 pixels
constexpr int WPR = W / 64;                   // 8 words per row
constexpr int WPI = H * WPR;                  // 4096 words per image
constexpr int WORDS_TOTAL = BATCH * WPI;      // 131072 words (1 MiB)

// ---------------- binarize: fp32 -> packed bits (ballot) ----------------
__global__ __launch_bounds__(256) void binarize_kernel(const float* __restrict__ in,
                                                       uint64_t* __restrict__ bits) {
    int idx = blockIdx.x * blockDim.x + threadIdx.x;   // one thread per pixel
    // TOTAL is a multiple of grid*block; no tail.
    int on = in[idx] >= 0.5f ? 1 : 0;
    uint64_t mask = __ballot(on);                      // bit = lane id
    if ((threadIdx.x & 63) == 0) {
        bits[idx >> 6] = mask;
    }
}

// ---------------- unpack: packed bits -> fp32 ----------------
__global__ __launch_bounds__(256) void unpack_kernel(const uint64_t* __restrict__ bits,
                                                     float* __restrict__ out) {
    int idx = blockIdx.x * blockDim.x + threadIdx.x;   // one thread per pixel
    uint64_t w = bits[idx >> 6];                       // wave-broadcast load
    out[idx] = (float)((w >> (idx & 63)) & 1ull);
}

// ---------------- bit-parallel Zhang-Suen substep ----------------
__device__ __forceinline__ void fadd(uint64_t a, uint64_t b, uint64_t c,
                                     uint64_t& s, uint64_t& cy) {
    uint64_t t = a ^ b;
    s = t ^ c;
    cy = (a & b) | (c & t);
}

template <bool FIRST>
__global__ __launch_bounds__(256) void substep_bits(const uint64_t* __restrict__ in,
                                                    uint64_t* __restrict__ out) {
    int idx = blockIdx.x * blockDim.x + threadIdx.x;   // one thread per word
    if (idx >= WORDS_TOTAL) return;
    int wc  = idx & (WPR - 1);          // word column 0..7
    int y   = (idx >> 3) & (H - 1);     // row 0..511
    const uint64_t* img = in + (idx - (y * WPR + wc)); // image base

    const int  rc   = y * WPR + wc;
    const bool hasL = (wc > 0), hasR = (wc < WPR - 1);
    const bool hasU = (y > 0),  hasD = (y < H - 1);

    uint64_t C  = img[rc];
    uint64_t L  = hasL ? img[rc - 1] : 0ull;
    uint64_t R  = hasR ? img[rc + 1] : 0ull;
    uint64_t U  = hasU ? img[rc - WPR] : 0ull;
    uint64_t UL = (hasU && hasL) ? img[rc - WPR - 1] : 0ull;
    uint64_t UR = (hasU && hasR) ? img[rc - WPR + 1] : 0ull;
    uint64_t D  = hasD ? img[rc + WPR] : 0ull;
    uint64_t DL = (hasD && hasL) ? img[rc + WPR - 1] : 0ull;
    uint64_t DR = (hasD && hasR) ? img[rc + WPR + 1] : 0ull;

    // Neighbor planes (bit i = that neighbor of pixel i)
    uint64_t p2 = U;                               // N
    uint64_t p3 = (U >> 1) | (UR << 63);           // NE
    uint64_t p4 = (C >> 1) | (R  << 63);           // E
    uint64_t p5 = (D >> 1) | (DR << 63);           // SE
    uint64_t p6 = D;                               // S
    uint64_t p7 = (D << 1) | (DL >> 63);           // SW
    uint64_t p8 = (C << 1) | (L  >> 63);           // W
    uint64_t p9 = (U << 1) | (UL >> 63);           // NW

    // ---- bcnt = popcount per bit of the 8 planes, via CSA tree ----
    uint64_t s1, ca, s2, cb, t0, t1, u, v;
    fadd(p2, p3, p4, s1, ca);
    fadd(p5, p6, p7, s2, cb);
    uint64_t s3 = p8 ^ p9, cc = p8 & p9;
    fadd(s1, s2, s3, t0, t1);                      // ones
    fadd(ca, cb, cc, u, v);                        // twos (u) + fours (v)
    uint64_t b1 = t1 ^ u, wv = t1 & u;             // twos bit, carry to fours
    uint64_t b2 = v ^ wv, b3 = v & wv;             // fours bit, eights bit
    uint64_t ge2 = b1 | b2 | b3;                   // bcnt >= 2
    uint64_t le6 = ~(b3 | (t0 & b1 & b2));         // bcnt <= 6 (exclude 7, 8)

    // ---- acnt == 1: exactly one 0->1 transition around the ring ----
    uint64_t a1 = ~p2 & p3, a2 = ~p3 & p4, a3 = ~p4 & p5, a4 = ~p5 & p6;
    uint64_t a5 = ~p6 & p7, a6 = ~p7 & p8, a7 = ~p8 & p9, a8 = ~p9 & p2;
    uint64_t q1, qa, q2, qb, r0, r1, qu, qv;
    fadd(a1, a2, a3, q1, qa);
    fadd(a4, a5, a6, q2, qb);
    uint64_t q3 = a7 ^ a8, qc = a7 & a8;
    fadd(q1, q2, q3, r0, r1);
    fadd(qa, qb, qc, qu, qv);
    uint64_t h1 = r1 ^ qu, hw = r1 & qu;
    uint64_t h2 = qv ^ hw, h3 = qv & hw;
    uint64_t exactly1 = r0 & ~(h1 | h2 | h3);

    // ---- directional conditions ----
    uint64_t cA, cB;
    if (FIRST) {
        cA = ~(p2 & p4 & p6);
        cB = ~(p4 & p6 & p8);
    } else {
        cA = ~(p2 & p4 & p8);
        cB = ~(p2 & p6 & p8);
    }

    uint64_t del = C & ge2 & le6 & exactly1 & cA & cB;
    out[idx] = C & ~del;
}

extern "C" void kernel_launch(void* const* d_in, const int* in_sizes, int n_in,
                              void* d_out, int out_size, void* d_ws, size_t ws_size,
                              hipStream_t stream) {
    const float* in0 = (const float*)d_in[0];
    float* out = (float*)d_out;

    uint64_t* A = (uint64_t*)d_ws;
    uint64_t* B = A + WORDS_TOTAL;   // 2 MiB total — ws is at least this big

    const int block = 256;
    const int pixGrid  = TOTAL / block;                 // 32768 blocks
    const int wordGrid = (WORDS_TOTAL + block - 1) / block;  // 512 blocks

    binarize_kernel<<<pixGrid, block, 0, stream>>>(in0, A);

    uint64_t* src = A;
    uint64_t* dst = B;
    bool first = true;
    for (int k = 0; k < 16; ++k) {
        if (first) {
            substep_bits<true><<<wordGrid, block, 0, stream>>>(src, dst);
        } else {
            substep_bits<false><<<wordGrid, block, 0, stream>>>(src, dst);
        }
        uint64_t* t = src; src = dst; dst = t;
        first = !first;
    }

    unpack_kernel<<<pixGrid, block, 0, stream>>>(src, out);
}

// Round 3
// 117.060 us; speedup vs baseline: 4.3124x; 1.2840x over previous
//
#include <hip/hip_runtime.h>
#include <stdint.h>

// Zhang-Suen skeletonization, fully fused single kernel.
// (32, 512, 512) fp32. 16 substeps (8 iterations x 2), bit-packed in LDS.
//
// Strategy: halo-redundant strips. Each block handles 64 valid rows of one
// image + 16 halo rows above/below (influence radius of 16 substeps). All 16
// substeps run in LDS with __syncthreads() between; the 64-row core is exact
// by the trapezoid argument (row at distance d from core is correct after
// substep s iff d <= 16-s). One kernel launch, no intermediate global traffic.
//
// Bit layout: bit i (LSB first) of word (r, wc) = pixel x = wc*64 + i, row r.

constexpr int W = 512;
constexpr int H = 512;
constexpr int BATCH = 32;
constexpr int WPR = W / 64;            // 8 words per row
constexpr int RV = 64;                 // valid rows per block
constexpr int HALO = 16;               // halo rows each side
constexpr int SR = RV + 2 * HALO;      // 96 strip rows
constexpr int LDW = WPR + 1;           // padded LDS row stride (9 words)
constexpr int STRIPS = H / RV;         // 8 strips per image
constexpr int NWORDS = SR * WPR;       // 768 words per strip
constexpr int THREADS = 768;           // 12 waves; 1 word/thread in substeps
constexpr int NWAVES = THREADS / 64;   // 12

__device__ __forceinline__ void fadd(uint64_t a, uint64_t b, uint64_t c,
                                     uint64_t& s, uint64_t& cy) {
    uint64_t t = a ^ b;
    s = t ^ c;
    cy = (a & b) | (c & t);
}

__device__ __forceinline__ uint64_t ldw(const uint64_t* buf, int r, int wc) {
    // rows outside the strip and word-columns outside the image read as 0
    return ((unsigned)r < (unsigned)SR && (unsigned)wc < (unsigned)WPR)
               ? buf[r * LDW + wc] : 0ull;
}

template <bool FIRST>
__device__ __forceinline__ void substep(const uint64_t* __restrict__ src,
                                        uint64_t* __restrict__ dst, int t) {
    int r  = t >> 3;       // 0..95
    int wc = t & 7;        // 0..7

    uint64_t C  = ldw(src, r,     wc);
    uint64_t L  = ldw(src, r,     wc - 1);
    uint64_t R  = ldw(src, r,     wc + 1);
    uint64_t U  = ldw(src, r - 1, wc);
    uint64_t UL = ldw(src, r - 1, wc - 1);
    uint64_t UR = ldw(src, r - 1, wc + 1);
    uint64_t D  = ldw(src, r + 1, wc);
    uint64_t DL = ldw(src, r + 1, wc - 1);
    uint64_t DR = ldw(src, r + 1, wc + 1);

    // Neighbor planes: P2=N P3=NE P4=E P5=SE P6=S P7=SW P8=W P9=NW
    uint64_t p2 = U;
    uint64_t p3 = (U >> 1) | (UR << 63);
    uint64_t p4 = (C >> 1) | (R  << 63);
    uint64_t p5 = (D >> 1) | (DR << 63);
    uint64_t p6 = D;
    uint64_t p7 = (D << 1) | (DL >> 63);
    uint64_t p8 = (C << 1) | (L  >> 63);
    uint64_t p9 = (U << 1) | (UL >> 63);

    // bcnt via CSA tree
    uint64_t s1, ca, s2, cb, t0, t1, u, v;
    fadd(p2, p3, p4, s1, ca);
    fadd(p5, p6, p7, s2, cb);
    uint64_t s3 = p8 ^ p9, cc = p8 & p9;
    fadd(s1, s2, s3, t0, t1);
    fadd(ca, cb, cc, u, v);
    uint64_t b1 = t1 ^ u, wv2 = t1 & u;
    uint64_t b2 = v ^ wv2, b3 = v & wv2;
    uint64_t ge2 = b1 | b2 | b3;
    uint64_t le6 = ~(b3 | (t0 & b1 & b2));

    // acnt == 1 (rising-edge count around the ring) via CSA tree
    uint64_t a1 = ~p2 & p3, a2 = ~p3 & p4, a3 = ~p4 & p5, a4 = ~p5 & p6;
    uint64_t a5 = ~p6 & p7, a6 = ~p7 & p8, a7 = ~p8 & p9, a8 = ~p9 & p2;
    uint64_t q1, qa, q2, qb, r0, r1, qu, qv;
    fadd(a1, a2, a3, q1, qa);
    fadd(a4, a5, a6, q2, qb);
    uint64_t q3 = a7 ^ a8, qc = a7 & a8;
    fadd(q1, q2, q3, r0, r1);
    fadd(qa, qb, qc, qu, qv);
    uint64_t h1 = r1 ^ qu, hw = r1 & qu;
    uint64_t h2 = qv ^ hw, h3 = qv & hw;
    uint64_t exactly1 = r0 & ~(h1 | h2 | h3);

    uint64_t cA, cB;
    if (FIRST) {
        cA = ~(p2 & p4 & p6);
        cB = ~(p4 & p6 & p8);
    } else {
        cA = ~(p2 & p4 & p8);
        cB = ~(p2 & p6 & p8);
    }

    uint64_t del = C & ge2 & le6 & exactly1 & cA & cB;
    dst[r * LDW + wc] = C & ~del;
}

__global__ __launch_bounds__(THREADS) void skel_fused(const float* __restrict__ in,
                                                      float* __restrict__ out) {
    __shared__ uint64_t buf0[SR * LDW];
    __shared__ uint64_t buf1[SR * LDW];

    const int blk  = blockIdx.x;
    const int img  = blk >> 3;          // image index 0..31
    const int s    = blk & 7;           // strip index 0..7
    const float* ibase = in  + (size_t)img * H * W;
    float*       obase = out + (size_t)img * H * W;

    const int t    = threadIdx.x;
    const int lane = t & 63;
    const int wv   = t >> 6;            // wave 0..11
    const int y0   = s * RV - HALO;     // first strip row (global, may be <0)

    // ---- binarize strip into buf0 (one wave -> one 64-px word via ballot) ----
    for (int w = wv; w < NWORDS; w += NWAVES) {
        int r  = w >> 3;
        int wc = w & 7;
        int gy = y0 + r;
        uint64_t m = 0ull;
        if ((unsigned)gy < (unsigned)H) {           // wave-uniform branch
            float f = ibase[gy * W + wc * 64 + lane];
            m = __ballot(f >= 0.5f);
        }
        if (lane == 0) buf0[r * LDW + wc] = m;
    }
    __syncthreads();

    // ---- 16 substeps (8 x {first, second}) entirely in LDS ----
    for (int it = 0; it < 8; ++it) {
        substep<true>(buf0, buf1, t);
        __syncthreads();
        substep<false>(buf1, buf0, t);
        __syncthreads();
    }

    // ---- unpack valid 64 rows to fp32 ----
    for (int w = wv; w < RV * WPR; w += NWAVES) {
        int r  = w >> 3;
        int wc = w & 7;
        uint64_t word = buf0[(r + HALO) * LDW + wc];   // broadcast read
        int gy = s * RV + r;
        obase[gy * W + wc * 64 + lane] = (float)((word >> lane) & 1ull);
    }
}

extern "C" void kernel_launch(void* const* d_in, const int* in_sizes, int n_in,
                              void* d_out, int out_size, void* d_ws, size_t ws_size,
                              hipStream_t stream) {
    const float* in0 = (const float*)d_in[0];
    float* out = (float*)d_out;

    const int grid = BATCH * STRIPS;   // 256 blocks, one per (image, strip)
    skel_fused<<<grid, THREADS, 0, stream>>>(in0, out);
}

// Round 4
// 92.795 us; speedup vs baseline: 5.4401x; 1.2615x over previous
//
#include <hip/hip_runtime.h>
#include <stdint.h>

// Zhang-Suen skeletonization, fully fused single kernel. (32,512,512) fp32.
// 16 substeps (8 iters x 2), bit-packed in LDS, halo-redundant 64-row strips.
//
// R4 changes vs R3:
//  - Guard-border LDS (zeroed once): straight-line ds_read_b64, no bounds checks
//  - acnt==1 via seen/conflict chain (cheaper than CSA); bcnt keeps CSA
//  - Early-out when a full iteration changes nothing (exact: fixed point)
//  - 4-wide ballot binarize, float4 unpack stores

constexpr int W = 512;
constexpr int H = 512;
constexpr int BATCH = 32;
constexpr int WPR = W / 64;            // 8 words per row
constexpr int RV = 64;                 // valid rows per block
constexpr int HALO = 16;               // halo rows each side (16 substeps)
constexpr int SR = RV + 2 * HALO;      // 96 strip rows
constexpr int STRIPS = H / RV;         // 8 strips per image
constexpr int NWORDS = SR * WPR;       // 768 interior words per strip
constexpr int THREADS = 768;           // 1 word/thread in substeps, 12 waves
constexpr int NWAVES = THREADS / 64;

// LDS layout with guard border: rows -1..SR, cols -1..WPR (+1 pad word)
constexpr int LDW2 = WPR + 2 + 1;      // 11 u64 row stride (odd -> bank spread)
constexpr int SRB = SR + 2;            // 98 rows
constexpr int BUFN = SRB * LDW2;       // 1078 u64 per buffer

__device__ __forceinline__ int lidx(int r, int wc) {  // r in [-1,SR], wc in [-1,WPR]
    return (r + 1) * LDW2 + (wc + 1);
}

__device__ __forceinline__ void fadd(uint64_t a, uint64_t b, uint64_t c,
                                     uint64_t& s, uint64_t& cy) {
    uint64_t t = a ^ b;
    s = t ^ c;
    cy = (a & b) | (c & t);
}

// One bit-parallel substep for one interior word. Reads 3x3 word neighborhood
// (guard border guarantees in-bounds), writes new word to dst, returns diff.
template <bool FIRST>
__device__ __forceinline__ uint64_t substep(const uint64_t* __restrict__ src,
                                            uint64_t* __restrict__ dst, int off) {
    const uint64_t* p = src + off;
    uint64_t UL = p[-LDW2 - 1], U = p[-LDW2], UR = p[-LDW2 + 1];
    uint64_t L  = p[-1],        C = p[0],     R  = p[1];
    uint64_t DL = p[ LDW2 - 1], D = p[ LDW2], DR = p[ LDW2 + 1];

    // Neighbor planes: P2=N P3=NE P4=E P5=SE P6=S P7=SW P8=W P9=NW
    uint64_t p2 = U;
    uint64_t p3 = (U >> 1) | (UR << 63);
    uint64_t p4 = (C >> 1) | (R  << 63);
    uint64_t p5 = (D >> 1) | (DR << 63);
    uint64_t p6 = D;
    uint64_t p7 = (D << 1) | (DL >> 63);
    uint64_t p8 = (C << 1) | (L  >> 63);
    uint64_t p9 = (U << 1) | (UL >> 63);

    // ---- bcnt in [2,6] via CSA tree ----
    uint64_t s1, ca, s2, cb, t0, t1, u, v;
    fadd(p2, p3, p4, s1, ca);
    fadd(p5, p6, p7, s2, cb);
    uint64_t s3 = p8 ^ p9, cc = p8 & p9;
    fadd(s1, s2, s3, t0, t1);          // ones
    fadd(ca, cb, cc, u, v);            // twos + fours
    uint64_t b1 = t1 ^ u, w2 = t1 & u; // twos bit, carry
    uint64_t b2 = v ^ w2, b3 = v & w2; // fours bit, eights bit
    uint64_t ge2 = b1 | b2 | b3;
    uint64_t le6 = ~(b3 | (t0 & b1 & b2));

    // ---- acnt == 1 via seen/conflict chain over rising edges ----
    uint64_t n2 = ~p2, n3 = ~p3, n4 = ~p4, n5 = ~p5;
    uint64_t n6 = ~p6, n7 = ~p7, n8 = ~p8, n9 = ~p9;
    uint64_t a1 = n2 & p3, a2 = n3 & p4, a3 = n4 & p5, a4 = n5 & p6;
    uint64_t a5 = n6 & p7, a6 = n7 & p8, a7 = n8 & p9, a8 = n9 & p2;
    uint64_t s = a1, c = 0;
    c |= s & a2; s |= a2;
    c |= s & a3; s |= a3;
    c |= s & a4; s |= a4;
    c |= s & a5; s |= a5;
    c |= s & a6; s |= a6;
    c |= s & a7; s |= a7;
    c |= s & a8; s |= a8;
    uint64_t exactly1 = s & ~c;

    uint64_t cA, cB;
    if (FIRST) {
        cA = ~(p2 & p4 & p6);
        cB = ~(p4 & p6 & p8);
    } else {
        cA = ~(p2 & p4 & p8);
        cB = ~(p2 & p6 & p8);
    }

    uint64_t del = C & ge2 & le6 & exactly1 & cA & cB;
    uint64_t newC = C & ~del;
    dst[off] = newC;
    return newC ^ C;                   // nonzero iff changed
}

__global__ __launch_bounds__(THREADS) void skel_fused(const float* __restrict__ in,
                                                      float* __restrict__ out) {
    __shared__ uint64_t buf0[BUFN];
    __shared__ uint64_t buf1[BUFN];

    const int blk  = blockIdx.x;
    const int img  = blk >> 3;          // image 0..31
    const int sidx = blk & 7;           // strip 0..7
    const float* ibase = in  + (size_t)img * H * W;
    float*       obase = out + (size_t)img * H * W;

    const int t    = threadIdx.x;
    const int lane = t & 63;
    const int wv   = t >> 6;            // wave 0..11
    const int y0   = sidx * RV - HALO;  // first strip row (global, may be <0)

    // ---- zero both buffers (borders stay 0 forever; interiors overwritten) ----
    for (int i = t; i < BUFN; i += THREADS) {
        buf0[i] = 0ull;
        buf1[i] = 0ull;
    }
    __syncthreads();

    // ---- binarize strip into buf0: each wave makes 4 words/iter via ballot ----
    for (int g = wv; g < NWORDS / 4; g += NWAVES) {   // 192 groups
        int r   = g >> 1;               // strip row 0..95
        int wcg = (g & 1) * 4;          // word-col group 0 or 4
        int gy  = y0 + r;
        if ((unsigned)gy < (unsigned)H) {             // wave-uniform
            const float* rp = ibase + gy * W + wcg * 64 + lane;
            uint64_t m0 = __ballot(rp[0]   >= 0.5f);
            uint64_t m1 = __ballot(rp[64]  >= 0.5f);
            uint64_t m2 = __ballot(rp[128] >= 0.5f);
            uint64_t m3 = __ballot(rp[192] >= 0.5f);
            if (lane == 0) {
                uint64_t* q = &buf0[lidx(r, wcg)];
                q[0] = m0; q[1] = m1; q[2] = m2; q[3] = m3;
            }
        }
    }
    __syncthreads();

    // ---- 16 substeps in LDS, early-out at fixed point (exact) ----
    const int r  = t >> 3;              // 0..95
    const int wc = t & 7;               // 0..7
    const int off = lidx(r, wc);

    for (int it = 0; it < 8; ++it) {
        uint64_t c1 = substep<true>(buf0, buf1, off);
        __syncthreads();
        uint64_t c2 = substep<false>(buf1, buf0, off);
        int any = __syncthreads_or((int)((c1 | c2) != 0ull));
        if (!any) break;                // whole padded strip is a fixed point
    }

    // ---- unpack valid 64 rows to fp32, float4 stores ----
    for (int g = wv; g < RV * WPR / 4; g += NWAVES) { // 128 groups of 256 px
        int r2    = g >> 1;             // valid row 0..63
        int halfw = (g & 1) * 4;        // word-col group 0 or 4
        int wcl   = halfw + (lane >> 4);
        uint64_t word = buf0[lidx(r2 + HALO, wcl)];
        int sh = (lane & 15) * 4;
        float4 v;
        v.x = (float)((word >> (sh + 0)) & 1ull);
        v.y = (float)((word >> (sh + 1)) & 1ull);
        v.z = (float)((word >> (sh + 2)) & 1ull);
        v.w = (float)((word >> (sh + 3)) & 1ull);
        int gy = sidx * RV + r2;
        *(float4*)(obase + gy * W + halfw * 64 + 4 * lane) = v;
    }
}

extern "C" void kernel_launch(void* const* d_in, const int* in_sizes, int n_in,
                              void* d_out, int out_size, void* d_ws, size_t ws_size,
                              hipStream_t stream) {
    const float* in0 = (const float*)d_in[0];
    float* out = (float*)d_out;

    const int grid = BATCH * STRIPS;   // 256 blocks, one per (image, strip)
    skel_fused<<<grid, THREADS, 0, stream>>>(in0, out);
}

// Round 5
// 91.736 us; speedup vs baseline: 5.5029x; 1.0115x over previous
//
#include <hip/hip_runtime.h>
#include <stdint.h>

// Zhang-Suen skeletonization, fully fused single kernel. (32,512,512) fp32.
// 16 substeps (8 iters x 2), bit-packed in LDS, halo-redundant 64-row strips.
//
// R5 changes vs R4:
//  - 1024 threads/block: 16 waves drive the binarize/unpack memory phases;
//    substeps use the first 768 threads (1 word each), rest park at barriers
//  - acnt==1 via balanced tree (shorter dep chain than sequential seen/conflict)
//  - C word carried in register across substeps: 8 LDS reads/substep, change
//    mask for the early-out computed from registers

constexpr int W = 512;
constexpr int H = 512;
constexpr int BATCH = 32;
constexpr int WPR = W / 64;            // 8 words per row
constexpr int RV = 64;                 // valid rows per block
constexpr int HALO = 16;               // halo rows each side (16 substeps)
constexpr int SR = RV + 2 * HALO;      // 96 strip rows
constexpr int STRIPS = H / RV;         // 8 strips per image
constexpr int NWORDS = SR * WPR;       // 768 interior words per strip
constexpr int THREADS = 1024;          // 16 waves
constexpr int NWAVES = THREADS / 64;

// LDS layout with guard border: rows -1..SR, cols -1..WPR (+1 pad word)
constexpr int LDW2 = WPR + 2 + 1;      // 11 u64 row stride (odd -> bank spread)
constexpr int SRB = SR + 2;            // 98 rows
constexpr int BUFN = SRB * LDW2;       // 1078 u64 per buffer

__device__ __forceinline__ int lidx(int r, int wc) {  // r in [-1,SR], wc in [-1,WPR]
    return (r + 1) * LDW2 + (wc + 1);
}

__device__ __forceinline__ void fadd(uint64_t a, uint64_t b, uint64_t c,
                                     uint64_t& s, uint64_t& cy) {
    uint64_t t = a ^ b;
    s = t ^ c;
    cy = (a & b) | (c & t);
}

// One bit-parallel substep for one interior word. C comes in by register;
// reads the other 8 neighbor words from LDS, writes newC to dst, returns it.
template <bool FIRST>
__device__ __forceinline__ uint64_t substep(const uint64_t* __restrict__ src,
                                            uint64_t* __restrict__ dst,
                                            int off, uint64_t C) {
    const uint64_t* p = src + off;
    uint64_t UL = p[-LDW2 - 1], U = p[-LDW2], UR = p[-LDW2 + 1];
    uint64_t L  = p[-1],                      R  = p[1];
    uint64_t DL = p[ LDW2 - 1], D = p[ LDW2], DR = p[ LDW2 + 1];

    // Neighbor planes: P2=N P3=NE P4=E P5=SE P6=S P7=SW P8=W P9=NW
    uint64_t p2 = U;
    uint64_t p3 = (U >> 1) | (UR << 63);
    uint64_t p4 = (C >> 1) | (R  << 63);
    uint64_t p5 = (D >> 1) | (DR << 63);
    uint64_t p6 = D;
    uint64_t p7 = (D << 1) | (DL >> 63);
    uint64_t p8 = (C << 1) | (L  >> 63);
    uint64_t p9 = (U << 1) | (UL >> 63);

    // ---- bcnt in [2,6] via CSA tree ----
    uint64_t s1, ca, s2, cb, t0, t1, u, v;
    fadd(p2, p3, p4, s1, ca);
    fadd(p5, p6, p7, s2, cb);
    uint64_t s3 = p8 ^ p9, cc = p8 & p9;
    fadd(s1, s2, s3, t0, t1);          // ones
    fadd(ca, cb, cc, u, v);            // twos + fours
    uint64_t b1 = t1 ^ u, w2 = t1 & u; // twos bit, carry
    uint64_t b2 = v ^ w2, b3 = v & w2; // fours bit, eights bit
    uint64_t bok = (b1 | b2) & ~(b3 | (t0 & b1 & b2));   // 2 <= bcnt <= 6

    // ---- acnt == 1 via balanced seen/conflict tree ----
    uint64_t a1 = ~p2 & p3, a2 = ~p3 & p4, a3 = ~p4 & p5, a4 = ~p5 & p6;
    uint64_t a5 = ~p6 & p7, a6 = ~p7 & p8, a7 = ~p8 & p9, a8 = ~p9 & p2;
    uint64_t t12 = a1 | a2, d12 = a1 & a2;
    uint64_t t34 = a3 | a4, d34 = a3 & a4;
    uint64_t t56 = a5 | a6, d56 = a5 & a6;
    uint64_t t78 = a7 | a8, d78 = a7 & a8;
    uint64_t s14 = t12 | t34, u14 = t12 & t34;
    uint64_t s58 = t56 | t78, u58 = t56 & t78;
    uint64_t seen = s14 | s58;
    uint64_t conf = (d12 | d34) | (d56 | d78) | (u14 | u58) | (s14 & s58);
    uint64_t exactly1 = seen & ~conf;

    uint64_t cA, cB;
    if (FIRST) {
        cA = ~(p2 & p4 & p6);
        cB = ~(p4 & p6 & p8);
    } else {
        cA = ~(p2 & p4 & p8);
        cB = ~(p2 & p6 & p8);
    }

    uint64_t del = C & bok & exactly1 & cA & cB;
    uint64_t newC = C & ~del;
    dst[off] = newC;
    return newC;
}

__global__ __launch_bounds__(THREADS) void skel_fused(const float* __restrict__ in,
                                                      float* __restrict__ out) {
    __shared__ uint64_t buf0[BUFN];
    __shared__ uint64_t buf1[BUFN];

    const int blk  = blockIdx.x;
    const int img  = blk >> 3;          // image 0..31
    const int sidx = blk & 7;           // strip 0..7
    const float* ibase = in  + (size_t)img * H * W;
    float*       obase = out + (size_t)img * H * W;

    const int t    = threadIdx.x;
    const int lane = t & 63;
    const int wv   = t >> 6;            // wave 0..15
    const int y0   = sidx * RV - HALO;  // first strip row (global, may be <0)

    // ---- zero both buffers (borders stay 0; interiors overwritten) ----
    for (int i = t; i < BUFN; i += THREADS) {
        buf0[i] = 0ull;
        buf1[i] = 0ull;
    }
    __syncthreads();

    // ---- binarize strip into buf0: each wave packs 4 words/iter via ballot ----
    for (int g = wv; g < NWORDS / 4; g += NWAVES) {   // 192 groups
        int r   = g >> 1;               // strip row 0..95
        int wcg = (g & 1) * 4;          // word-col group 0 or 4
        int gy  = y0 + r;
        if ((unsigned)gy < (unsigned)H) {             // wave-uniform
            const float* rp = ibase + gy * W + wcg * 64 + lane;
            uint64_t m0 = __ballot(rp[0]   >= 0.5f);
            uint64_t m1 = __ballot(rp[64]  >= 0.5f);
            uint64_t m2 = __ballot(rp[128] >= 0.5f);
            uint64_t m3 = __ballot(rp[192] >= 0.5f);
            if (lane == 0) {
                uint64_t* q = &buf0[lidx(r, wcg)];
                q[0] = m0; q[1] = m1; q[2] = m2; q[3] = m3;
            }
        }
    }
    __syncthreads();

    // ---- 16 substeps in LDS, early-out at fixed point (exact) ----
    const bool worker = (t < NWORDS);   // first 12 waves do substep work
    const int  r   = t >> 3;            // 0..95 (workers)
    const int  wc  = t & 7;             // 0..7
    const int  off = worker ? lidx(r, wc) : lidx(0, 0);

    uint64_t creg = worker ? buf0[off] : 0ull;

    for (int it = 0; it < 8; ++it) {
        uint64_t n1 = creg, n2 = creg;
        if (worker) n1 = substep<true>(buf0, buf1, off, creg);
        __syncthreads();
        if (worker) n2 = substep<false>(buf1, buf0, off, n1);
        uint64_t chg = (n1 ^ creg) | (n2 ^ n1);
        creg = n2;
        int any = __syncthreads_or((int)(chg != 0ull));
        if (!any) break;                // whole padded strip is a fixed point
    }

    // ---- unpack valid 64 rows to fp32, float4 stores ----
    for (int g = wv; g < RV * WPR / 4; g += NWAVES) { // 128 groups of 256 px
        int r2    = g >> 1;             // valid row 0..63
        int halfw = (g & 1) * 4;        // word-col group 0 or 4
        int wcl   = halfw + (lane >> 4);
        uint64_t word = buf0[lidx(r2 + HALO, wcl)];   // 16-lane broadcast read
        int sh = (lane & 15) * 4;
        float4 v;
        v.x = (float)((word >> (sh + 0)) & 1ull);
        v.y = (float)((word >> (sh + 1)) & 1ull);
        v.z = (float)((word >> (sh + 2)) & 1ull);
        v.w = (float)((word >> (sh + 3)) & 1ull);
        int gy = sidx * RV + r2;
        *(float4*)(obase + gy * W + halfw * 64 + 4 * lane) = v;
    }
}

extern "C" void kernel_launch(void* const* d_in, const int* in_sizes, int n_in,
                              void* d_out, int out_size, void* d_ws, size_t ws_size,
                              hipStream_t stream) {
    const float* in0 = (const float*)d_in[0];
    float* out = (float*)d_out;

    const int grid = BATCH * STRIPS;   // 256 blocks, one per (image, strip)
    skel_fused<<<grid, THREADS, 0, stream>>>(in0, out);
}